// Round 2
// baseline (460.316 us; speedup 1.0000x reference)
//
#include <hip/hip_runtime.h>

#define BATCH 8
#define CCH 8
#define HW 262144       // 512*512
#define SEGS 16         // segments 1..16 (segment 0 is provably ignored by the reference)
#define GX 128          // blocks per batch; grid = (GX, BATCH) = 1024 blocks = 4/CU

// ws float layout:
//   [0, 128)      counts[b][s]
//   [128, 1152)   sums[b][s][c]
//   [1152, 1280)  pen_sum[b][s]

// ---------------------------------------------------------------------------
// Pass 1: counts + per-channel sums. One-hot register accumulation (no LDS
// atomics). Wave w owns channels {2w, 2w+1} over the block's whole pixel
// range; counts are computed redundantly per wave, committed by wave 0 only.
// ---------------------------------------------------------------------------
__global__ __launch_bounds__(256) void accum_kernel(
    const float* __restrict__ emb, const int* __restrict__ lab,
    const int* __restrict__ msk, float* __restrict__ ws)
{
    const int b = blockIdx.y;
    const int wave = threadIdx.x >> 6;
    const int lane = threadIdx.x & 63;
    const int c0 = wave * 2;

    float s0[SEGS], s1[SEGS], cnt[SEGS];
#pragma unroll
    for (int s = 0; s < SEGS; ++s) { s0[s] = 0.f; s1[s] = 0.f; cnt[s] = 0.f; }

    const float* eb = emb + (size_t)b * CCH * HW;
    const int4* lb = (const int4*)(lab + (size_t)b * HW);
    const int4* mb = (const int4*)(msk + (size_t)b * HW);
    const float4* ep0 = (const float4*)(eb + (size_t)c0 * HW);
    const float4* ep1 = (const float4*)(eb + (size_t)(c0 + 1) * HW);

    const int ng = HW / 4;   // 65536 int4-groups; grid covers exactly, no tail
    for (int base = blockIdx.x * 256; base < ng; base += GX * 256) {
#pragma unroll
        for (int q = 0; q < 4; ++q) {
            const int g = base + (q << 6) + lane;
            int4 l4 = lb[g];
            int4 m4 = mb[g];
            float4 ea = ep0[g];
            float4 ec = ep1[g];
            int id[4] = { m4.x ? l4.x : 0, m4.y ? l4.y : 0,
                          m4.z ? l4.z : 0, m4.w ? l4.w : 0 };
            float e0[4] = { ea.x, ea.y, ea.z, ea.w };
            float e1[4] = { ec.x, ec.y, ec.z, ec.w };
#pragma unroll
            for (int j = 0; j < 4; ++j) {
#pragma unroll
                for (int s = 0; s < SEGS; ++s) {
                    float oh = (id[j] == s + 1) ? 1.0f : 0.0f;
                    cnt[s] += oh;
                    s0[s] = fmaf(oh, e0[j], s0[s]);
                    s1[s] = fmaf(oh, e1[j], s1[s]);
                }
            }
        }
    }

    // 64-lane butterfly reduction; lane 0 commits via global atomics
#pragma unroll
    for (int s = 0; s < SEGS; ++s) {
#pragma unroll
        for (int m = 32; m >= 1; m >>= 1) {
            s0[s]  += __shfl_xor(s0[s], m);
            s1[s]  += __shfl_xor(s1[s], m);
            cnt[s] += __shfl_xor(cnt[s], m);
        }
    }
    if (lane == 0) {
#pragma unroll
        for (int s = 0; s < SEGS; ++s) {
            if (s0[s] != 0.f) atomicAdd(&ws[128 + (b * SEGS + s) * CCH + c0],     s0[s]);
            if (s1[s] != 0.f) atomicAdd(&ws[128 + (b * SEGS + s) * CCH + c0 + 1], s1[s]);
        }
        if (wave == 0) {
#pragma unroll
            for (int s = 0; s < SEGS; ++s)
                if (cnt[s] != 0.f) atomicAdd(&ws[b * SEGS + s], cnt[s]);
        }
    }
}

// ---------------------------------------------------------------------------
// Pass 2: hinged pull penalties. Register pens[16] one-hot accumulation
// (no LDS atomics); mean table in LDS is broadcast-only (16-word rows).
// ---------------------------------------------------------------------------
__global__ __launch_bounds__(256) void pull_kernel(
    const float* __restrict__ emb, const int* __restrict__ lab,
    const int* __restrict__ msk, float* __restrict__ ws)
{
    const int b = blockIdx.y;
    const int lane = threadIdx.x & 63;
    __shared__ float mt[CCH][SEGS];   // transposed means

    if (threadIdx.x < SEGS * CCH) {
        int s = threadIdx.x & (SEGS - 1);
        int c = threadIdx.x >> 4;
        float cv = ws[b * SEGS + s];
        mt[c][s] = ws[128 + (b * SEGS + s) * CCH + c] / fmaxf(cv, 1.0f);
    }
    __syncthreads();

    float pens[SEGS];
#pragma unroll
    for (int s = 0; s < SEGS; ++s) pens[s] = 0.f;

    const float* eb = emb + (size_t)b * CCH * HW;
    const int4* lb = (const int4*)(lab + (size_t)b * HW);
    const int4* mb = (const int4*)(msk + (size_t)b * HW);

    const int ng = HW / 4;
    for (int g = blockIdx.x * 256 + threadIdx.x; g < ng; g += GX * 256) {
        int4 l4 = lb[g];
        int4 m4 = mb[g];
        int id[4] = { m4.x ? l4.x : 0, m4.y ? l4.y : 0,
                      m4.z ? l4.z : 0, m4.w ? l4.w : 0 };
        int ix[4];
#pragma unroll
        for (int j = 0; j < 4; ++j) ix[j] = id[j] ? id[j] - 1 : 0;
        float ss[4] = { 0.f, 0.f, 0.f, 0.f };
#pragma unroll
        for (int c = 0; c < CCH; ++c) {
            float4 e4 = ((const float4*)(eb + (size_t)c * HW))[g];
            float ev[4] = { e4.x, e4.y, e4.z, e4.w };
#pragma unroll
            for (int j = 0; j < 4; ++j) {
                float d = ev[j] - mt[c][ix[j]];
                ss[j] = fmaf(d, d, ss[j]);
            }
        }
#pragma unroll
        for (int j = 0; j < 4; ++j) {
            float d = sqrtf(fmaxf(ss[j], 1e-12f));
            float h = fmaxf(d - 0.5f, 0.f);
            float h2 = h * h;
#pragma unroll
            for (int s = 0; s < SEGS; ++s)
                pens[s] += (id[j] == s + 1) ? h2 : 0.f;
        }
    }

#pragma unroll
    for (int s = 0; s < SEGS; ++s) {
#pragma unroll
        for (int m = 32; m >= 1; m >>= 1) pens[s] += __shfl_xor(pens[s], m);
    }
    if (lane == 0) {
#pragma unroll
        for (int s = 0; s < SEGS; ++s)
            if (pens[s] != 0.f) atomicAdd(&ws[1152 + b * SEGS + s], pens[s]);
    }
}

// ---------------------------------------------------------------------------
// Pass 3: finalize (unchanged from the verified round-0 kernel)
// ---------------------------------------------------------------------------
__global__ __launch_bounds__(256) void finalize_kernel(
    const float* __restrict__ ws, float* __restrict__ out)
{
    __shared__ float cnt[BATCH][SEGS];
    __shared__ float mu[BATCH][SEGS][CCH];
    __shared__ float pen[BATCH][SEGS];
    __shared__ float res[BATCH][3];

    for (int i = threadIdx.x; i < BATCH * SEGS; i += 256) {
        (&cnt[0][0])[i] = ws[i];
        (&pen[0][0])[i] = ws[1152 + i];
    }
    for (int i = threadIdx.x; i < BATCH * SEGS * CCH; i += 256) {
        float c = ws[i / CCH];
        (&mu[0][0][0])[i] = ws[128 + i] / fmaxf(c, 1.0f);
    }
    __syncthreads();

    const int b = threadIdx.x >> 5;   // 8 batches x 32-lane groups
    const int l = threadIdx.x & 31;

    float pullv = 0.f, Kf = 0.f;
    if (l < SEGS && cnt[b][l] > 0.f) {
        Kf = 1.f;
        pullv = pen[b][l] / cnt[b][l];       // count>0 => max(count,1)=count
    }
    float hs = 0.f, np = 0.f;
    for (int p = l; p < 256; p += 32) {
        int i = p >> 4, j = p & 15;
        if (i < j && cnt[b][i] > 0.f && cnt[b][j] > 0.f) {
            float ssq = 0.f;
#pragma unroll
            for (int c = 0; c < CCH; ++c) {
                float d = mu[b][i][c] - mu[b][j][c];
                ssq += d * d;
            }
            float dist = sqrtf(fmaxf(ssq, 1e-12f));
            float h = fmaxf(3.0f - dist, 0.f);   // 2*DELTA_D = 3.0
            hs += h * h;
            np += 1.f;
        }
    }
#pragma unroll
    for (int m = 16; m >= 1; m >>= 1) {
        pullv += __shfl_xor(pullv, m);
        Kf    += __shfl_xor(Kf, m);
        hs    += __shfl_xor(hs, m);
        np    += __shfl_xor(np, m);
    }
    if (l == 0) {
        res[b][0] = (Kf > 0.f) ? pullv / Kf : 0.f;
        res[b][1] = (np > 0.f) ? hs / np : 0.f;
        res[b][2] = (Kf > 0.f) ? 1.f : 0.f;
    }
    __syncthreads();
    if (threadIdx.x == 0) {
        float sp = 0.f, sh = 0.f, nv = 0.f;
        for (int bb = 0; bb < BATCH; ++bb) {
            sp += res[bb][0] * res[bb][2];
            sh += res[bb][1] * res[bb][2];
            nv += res[bb][2];
        }
        nv = fmaxf(nv, 1.f);
        out[0] = sp / nv;
        out[1] = sh / nv;
    }
}

extern "C" void kernel_launch(void* const* d_in, const int* in_sizes, int n_in,
                              void* d_out, int out_size, void* d_ws, size_t ws_size,
                              hipStream_t stream)
{
    const float* emb = (const float*)d_in[0];
    const int* lab = (const int*)d_in[1];
    const int* msk = (const int*)d_in[2];
    float* out = (float*)d_out;
    float* ws = (float*)d_ws;

    hipMemsetAsync(d_ws, 0, 1280 * sizeof(float), stream);
    dim3 grid(GX, BATCH);
    accum_kernel<<<grid, 256, 0, stream>>>(emb, lab, msk, ws);
    pull_kernel<<<grid, 256, 0, stream>>>(emb, lab, msk, ws);
    finalize_kernel<<<1, 256, 0, stream>>>(ws, out);
}

// Round 3
// 162.340 us; speedup vs baseline: 2.8355x; 2.8355x over previous
//
#include <hip/hip_runtime.h>

#define BATCH 8
#define CCH 8
#define HW 262144       // 512*512
#define SEGS 16         // segments 1..16 (segment 0 is provably ignored by the reference)
#define GX 256          // blocks per batch; GX*256 threads == HW/4 groups exactly (no loop)

// ws float layout:
//   [0, 128)      counts[b][s]
//   [128, 1152)   sums[b][s][c]
//   [1152, 1280)  pen_sum[b][s]

// ---------------------------------------------------------------------------
// Pass 1: counts + per-channel sums. One int4-group (4 pixels) per thread.
// All 10 global loads issued as an independent batch BEFORE any use -> the
// wave has 10 outstanding HBM loads instead of 1 (round-0 was latency-bound
// on serialized load->use->load chains). LDS atomic scatter is measured-cheap
// (~0.6 us chip-wide) and stays.
// ---------------------------------------------------------------------------
__global__ __launch_bounds__(256, 4) void accum_kernel(
    const float* __restrict__ emb, const int* __restrict__ lab,
    const int* __restrict__ msk, float* __restrict__ ws)
{
    const int b = blockIdx.y;
    const int wave = threadIdx.x >> 6;
    __shared__ float lsum[4][SEGS][CCH];
    __shared__ float lcnt[4][SEGS];
    for (int i = threadIdx.x; i < 4 * SEGS * CCH; i += 256) (&lsum[0][0][0])[i] = 0.f;
    for (int i = threadIdx.x; i < 4 * SEGS; i += 256) (&lcnt[0][0])[i] = 0.f;
    __syncthreads();

    const int g = blockIdx.x * 256 + threadIdx.x;   // one group per thread, exact cover

    // ---- batched independent loads (10 outstanding) ----
    const int4 l4 = ((const int4*)(lab + (size_t)b * HW))[g];
    const int4 m4 = ((const int4*)(msk + (size_t)b * HW))[g];
    const float4* ep = (const float4*)(emb + (size_t)b * CCH * HW);
    float4 e[CCH];
#pragma unroll
    for (int c = 0; c < CCH; ++c) e[c] = ep[(size_t)c * (HW / 4) + g];

    const int id0 = m4.x ? l4.x : 0;
    const int id1 = m4.y ? l4.y : 0;
    const int id2 = m4.z ? l4.z : 0;
    const int id3 = m4.w ? l4.w : 0;

    if (id0) atomicAdd(&lcnt[wave][id0 - 1], 1.f);
    if (id1) atomicAdd(&lcnt[wave][id1 - 1], 1.f);
    if (id2) atomicAdd(&lcnt[wave][id2 - 1], 1.f);
    if (id3) atomicAdd(&lcnt[wave][id3 - 1], 1.f);
#pragma unroll
    for (int c = 0; c < CCH; ++c) {
        if (id0) atomicAdd(&lsum[wave][id0 - 1][c], e[c].x);
        if (id1) atomicAdd(&lsum[wave][id1 - 1][c], e[c].y);
        if (id2) atomicAdd(&lsum[wave][id2 - 1][c], e[c].z);
        if (id3) atomicAdd(&lsum[wave][id3 - 1][c], e[c].w);
    }

    __syncthreads();
    for (int i = threadIdx.x; i < SEGS * CCH; i += 256) {
        float v = (&lsum[0][0][0])[i] + (&lsum[1][0][0])[i]
                + (&lsum[2][0][0])[i] + (&lsum[3][0][0])[i];
        if (v != 0.f) atomicAdd(&ws[128 + b * SEGS * CCH + i], v);
    }
    for (int i = threadIdx.x; i < SEGS; i += 256) {
        float v = lcnt[0][i] + lcnt[1][i] + lcnt[2][i] + lcnt[3][i];
        if (v != 0.f) atomicAdd(&ws[b * SEGS + i], v);
    }
}

// ---------------------------------------------------------------------------
// Pass 2: hinged pull penalties. Same batched-load structure. Mean table in
// LDS transposed [c][s]: for fixed c, 16 distinct words -> 16 distinct banks,
// same-address reads broadcast -> conflict-free.
// ---------------------------------------------------------------------------
__global__ __launch_bounds__(256, 4) void pull_kernel(
    const float* __restrict__ emb, const int* __restrict__ lab,
    const int* __restrict__ msk, float* __restrict__ ws)
{
    const int b = blockIdx.y;
    const int wave = threadIdx.x >> 6;
    __shared__ float mt[CCH][SEGS];
    __shared__ float lpen[4][SEGS];
    for (int i = threadIdx.x; i < 4 * SEGS; i += 256) (&lpen[0][0])[i] = 0.f;
    if (threadIdx.x < SEGS * CCH) {
        int s = threadIdx.x & (SEGS - 1);
        int c = threadIdx.x >> 4;
        float cv = ws[b * SEGS + s];
        mt[c][s] = ws[128 + (b * SEGS + s) * CCH + c] / fmaxf(cv, 1.0f);
    }
    __syncthreads();

    const int g = blockIdx.x * 256 + threadIdx.x;

    // ---- batched independent loads (10 outstanding) ----
    const int4 l4 = ((const int4*)(lab + (size_t)b * HW))[g];
    const int4 m4 = ((const int4*)(msk + (size_t)b * HW))[g];
    const float4* ep = (const float4*)(emb + (size_t)b * CCH * HW);
    float4 e[CCH];
#pragma unroll
    for (int c = 0; c < CCH; ++c) e[c] = ep[(size_t)c * (HW / 4) + g];

    const int id0 = m4.x ? l4.x : 0;
    const int id1 = m4.y ? l4.y : 0;
    const int id2 = m4.z ? l4.z : 0;
    const int id3 = m4.w ? l4.w : 0;
    const int ix0 = id0 ? id0 - 1 : 0;
    const int ix1 = id1 ? id1 - 1 : 0;
    const int ix2 = id2 ? id2 - 1 : 0;
    const int ix3 = id3 ? id3 - 1 : 0;

    float ss0 = 0.f, ss1 = 0.f, ss2 = 0.f, ss3 = 0.f;
#pragma unroll
    for (int c = 0; c < CCH; ++c) {
        float d0 = e[c].x - mt[c][ix0];
        float d1 = e[c].y - mt[c][ix1];
        float d2 = e[c].z - mt[c][ix2];
        float d3 = e[c].w - mt[c][ix3];
        ss0 = fmaf(d0, d0, ss0);
        ss1 = fmaf(d1, d1, ss1);
        ss2 = fmaf(d2, d2, ss2);
        ss3 = fmaf(d3, d3, ss3);
    }
    if (id0) { float d = sqrtf(fmaxf(ss0, 1e-12f)); float h = fmaxf(d - 0.5f, 0.f); atomicAdd(&lpen[wave][ix0], h * h); }
    if (id1) { float d = sqrtf(fmaxf(ss1, 1e-12f)); float h = fmaxf(d - 0.5f, 0.f); atomicAdd(&lpen[wave][ix1], h * h); }
    if (id2) { float d = sqrtf(fmaxf(ss2, 1e-12f)); float h = fmaxf(d - 0.5f, 0.f); atomicAdd(&lpen[wave][ix2], h * h); }
    if (id3) { float d = sqrtf(fmaxf(ss3, 1e-12f)); float h = fmaxf(d - 0.5f, 0.f); atomicAdd(&lpen[wave][ix3], h * h); }

    __syncthreads();
    for (int i = threadIdx.x; i < SEGS; i += 256) {
        float v = lpen[0][i] + lpen[1][i] + lpen[2][i] + lpen[3][i];
        if (v != 0.f) atomicAdd(&ws[1152 + b * SEGS + i], v);
    }
}

// ---------------------------------------------------------------------------
// Pass 3: finalize (unchanged from the verified round-0 kernel)
// ---------------------------------------------------------------------------
__global__ __launch_bounds__(256) void finalize_kernel(
    const float* __restrict__ ws, float* __restrict__ out)
{
    __shared__ float cnt[BATCH][SEGS];
    __shared__ float mu[BATCH][SEGS][CCH];
    __shared__ float pen[BATCH][SEGS];
    __shared__ float res[BATCH][3];

    for (int i = threadIdx.x; i < BATCH * SEGS; i += 256) {
        (&cnt[0][0])[i] = ws[i];
        (&pen[0][0])[i] = ws[1152 + i];
    }
    for (int i = threadIdx.x; i < BATCH * SEGS * CCH; i += 256) {
        float c = ws[i / CCH];
        (&mu[0][0][0])[i] = ws[128 + i] / fmaxf(c, 1.0f);
    }
    __syncthreads();

    const int b = threadIdx.x >> 5;   // 8 batches x 32-lane groups
    const int l = threadIdx.x & 31;

    float pullv = 0.f, Kf = 0.f;
    if (l < SEGS && cnt[b][l] > 0.f) {
        Kf = 1.f;
        pullv = pen[b][l] / cnt[b][l];       // count>0 => max(count,1)=count
    }
    float hs = 0.f, np = 0.f;
    for (int p = l; p < 256; p += 32) {
        int i = p >> 4, j = p & 15;
        if (i < j && cnt[b][i] > 0.f && cnt[b][j] > 0.f) {
            float ssq = 0.f;
#pragma unroll
            for (int c = 0; c < CCH; ++c) {
                float d = mu[b][i][c] - mu[b][j][c];
                ssq += d * d;
            }
            float dist = sqrtf(fmaxf(ssq, 1e-12f));
            float h = fmaxf(3.0f - dist, 0.f);   // 2*DELTA_D = 3.0
            hs += h * h;
            np += 1.f;
        }
    }
#pragma unroll
    for (int m = 16; m >= 1; m >>= 1) {
        pullv += __shfl_xor(pullv, m);
        Kf    += __shfl_xor(Kf, m);
        hs    += __shfl_xor(hs, m);
        np    += __shfl_xor(np, m);
    }
    if (l == 0) {
        res[b][0] = (Kf > 0.f) ? pullv / Kf : 0.f;
        res[b][1] = (np > 0.f) ? hs / np : 0.f;
        res[b][2] = (Kf > 0.f) ? 1.f : 0.f;
    }
    __syncthreads();
    if (threadIdx.x == 0) {
        float sp = 0.f, sh = 0.f, nv = 0.f;
        for (int bb = 0; bb < BATCH; ++bb) {
            sp += res[bb][0] * res[bb][2];
            sh += res[bb][1] * res[bb][2];
            nv += res[bb][2];
        }
        nv = fmaxf(nv, 1.f);
        out[0] = sp / nv;
        out[1] = sh / nv;
    }
}

extern "C" void kernel_launch(void* const* d_in, const int* in_sizes, int n_in,
                              void* d_out, int out_size, void* d_ws, size_t ws_size,
                              hipStream_t stream)
{
    const float* emb = (const float*)d_in[0];
    const int* lab = (const int*)d_in[1];
    const int* msk = (const int*)d_in[2];
    float* out = (float*)d_out;
    float* ws = (float*)d_ws;

    hipMemsetAsync(d_ws, 0, 1280 * sizeof(float), stream);
    dim3 grid(GX, BATCH);
    accum_kernel<<<grid, 256, 0, stream>>>(emb, lab, msk, ws);
    pull_kernel<<<grid, 256, 0, stream>>>(emb, lab, msk, ws);
    finalize_kernel<<<1, 256, 0, stream>>>(ws, out);
}